// Round 5
// baseline (150.016 us; speedup 1.0000x reference)
//
#include <hip/hip_runtime.h>

#define N_RAYS 262144
#define N_SAMPLES 128

typedef float vf2 __attribute__((ext_vector_type(2)));

// One wave (64 lanes) per ray; 2 consecutive samples per lane.
// Colors are loaded fully unit-stride (3 rounds of 64-lane float2) and
// matched to weights via a wave-local LDS redistribution.
__global__ __launch_bounds__(256) void volrend_kernel(
    const float* __restrict__ sigma,
    const float* __restrict__ colors,
    const float* __restrict__ z_vals,
    const float* __restrict__ rays_d,
    float* __restrict__ out)
{
    const int wid  = threadIdx.x >> 6;   // wave in block: 0..3
    const int lane = threadIdx.x & 63;
    const int ray  = blockIdx.x * 4 + wid;

    __shared__ float wlds[4][N_SAMPLES]; // per-wave weights for redistribution
    __shared__ float sred[4][6];         // per-ray: cr,cg,cb,depth,disp,acc

    // ---- issue global loads up front ----
    const int s0 = lane * 2;
    const size_t rbase = (size_t)ray * N_SAMPLES;
    const vf2 zv = __builtin_nontemporal_load(
        reinterpret_cast<const vf2*>(z_vals + rbase + s0));
    const vf2 sg = __builtin_nontemporal_load(
        reinterpret_cast<const vf2*>(sigma + rbase + s0));
    // colors: 3 unit-stride rounds; element e = j*128 + 2*lane of this ray's
    // 384-float color segment. sample = e/3, channel = e%3.
    const float* cseg = colors + rbase * 3;
    const vf2 cv0 = __builtin_nontemporal_load(
        reinterpret_cast<const vf2*>(cseg + 0 * 128 + 2 * lane));
    const vf2 cv1 = __builtin_nontemporal_load(
        reinterpret_cast<const vf2*>(cseg + 1 * 128 + 2 * lane));
    const vf2 cv2 = __builtin_nontemporal_load(
        reinterpret_cast<const vf2*>(cseg + 2 * 128 + 2 * lane));
    const float dx = rays_d[ray * 3 + 0];
    const float dy = rays_d[ray * 3 + 1];
    const float dz = rays_d[ray * 3 + 2];

    const float nrm = sqrtf(dx * dx + dy * dy + dz * dz);

    // ---- dists ----
    const float z_next = __shfl_down(zv.x, 1, 64);       // z[s0+2]
    const float dist0 = (zv.y - zv.x) * nrm;
    const float dist1 = (lane == 63) ? (1e10f * nrm) : (z_next - zv.y) * nrm;

    // ---- alpha / survival ----
    const float e0 = __expf(-fmaxf(sg.x, 0.0f) * dist0);
    const float e1 = __expf(-fmaxf(sg.y, 0.0f) * dist1);
    const float alpha0 = 1.0f - e0;
    const float alpha1 = 1.0f - e1;
    const float a0 = e0 + 1e-10f;   // (1 - alpha) + 1e-10
    const float a1 = e1 + 1e-10f;

    // ---- exclusive prefix product over 128 samples (2/lane) ----
    float scan = a0 * a1;
    #pragma unroll
    for (int off = 1; off < 64; off <<= 1) {
        const float n = __shfl_up(scan, off, 64);
        if (lane >= off) scan *= n;
    }
    float excl = __shfl_up(scan, 1, 64);
    if (lane == 0) excl = 1.0f;

    const float w0 = excl * alpha0;
    const float w1 = excl * a0 * alpha1;

    // ---- weights: global store + wave-local LDS for color matching ----
    const size_t R = N_RAYS;
    vf2 wv; wv.x = w0; wv.y = w1;
    __builtin_nontemporal_store(
        wv, reinterpret_cast<vf2*>(out + 3 * R + rbase + s0));
    *reinterpret_cast<vf2*>(&wlds[wid][s0]) = wv;

    // ---- rgb accumulation (rotation-indexed, compile-time A indices) ----
    // channel of element e: c = (t_j + b) % 3, t_j = (j*128)%3 = {0,2,1},
    // b = (2*lane)%3. Accumulate into A[(c - b) mod 3] = A[(t_j+parity)%3].
    float A0 = 0.0f, A1 = 0.0f, A2 = 0.0f;
    {
        const int eb = 2 * lane;
        // j = 0 (t=0): A0 += w[e/3]*v.x ; A1 += w[(e+1)/3]*v.y
        A0 += wlds[wid][(0 * 128 + eb) / 3] * cv0.x;
        A1 += wlds[wid][(0 * 128 + eb + 1) / 3] * cv0.y;
        // j = 1 (t=2): A2, A0
        A2 += wlds[wid][(1 * 128 + eb) / 3] * cv1.x;
        A0 += wlds[wid][(1 * 128 + eb + 1) / 3] * cv1.y;
        // j = 2 (t=1): A1, A2
        A1 += wlds[wid][(2 * 128 + eb) / 3] * cv2.x;
        A2 += wlds[wid][(2 * 128 + eb + 1) / 3] * cv2.y;
    }
    // un-rotate: channel c sum = A[(c - b) mod 3]
    const int b = (2 * lane) % 3;
    float cr = (b == 0) ? A0 : (b == 1) ? A2 : A1;
    float cg = (b == 0) ? A1 : (b == 1) ? A0 : A2;
    float cb = (b == 0) ? A2 : (b == 1) ? A1 : A0;

    // ---- reductions ----
    float acc   = w0 + w1;
    float depth = w0 * zv.x + w1 * zv.y;
    #pragma unroll
    for (int off = 32; off; off >>= 1) {
        acc   += __shfl_xor(acc,   off, 64);
        depth += __shfl_xor(depth, off, 64);
        cr    += __shfl_xor(cr,    off, 64);
        cg    += __shfl_xor(cg,    off, 64);
        cb    += __shfl_xor(cb,    off, 64);
    }

    if (lane == 0) {
        sred[wid][0] = cr;
        sred[wid][1] = cg;
        sred[wid][2] = cb;
        sred[wid][3] = depth;
        sred[wid][4] = 1.0f / fmaxf(1e-10f, depth / acc);
        sred[wid][5] = acc;
    }
    __syncthreads();

    // ---- coalesced epilogue: one multi-lane store per output segment ----
    // out layout (flat, f32): rgb[R,3] | weights[R,128] | depth[R] | disp[R] | acc[R]
    const int t = threadIdx.x;
    if (t < 12) {                       // rgb: 12 consecutive floats per block
        out[(size_t)blockIdx.x * 12 + t] = sred[t / 3][t % 3];
    } else if (t < 16) {                // depth
        out[131 * R + (size_t)blockIdx.x * 4 + (t - 12)] = sred[t - 12][3];
    } else if (t < 20) {                // disp
        out[132 * R + (size_t)blockIdx.x * 4 + (t - 16)] = sred[t - 16][4];
    } else if (t < 24) {                // acc
        out[133 * R + (size_t)blockIdx.x * 4 + (t - 20)] = sred[t - 20][5];
    }
}

extern "C" void kernel_launch(void* const* d_in, const int* in_sizes, int n_in,
                              void* d_out, int out_size, void* d_ws, size_t ws_size,
                              hipStream_t stream) {
    const float* sigma  = (const float*)d_in[0];
    const float* colors = (const float*)d_in[1];
    const float* z_vals = (const float*)d_in[2];
    const float* rays_d = (const float*)d_in[3];
    float* out = (float*)d_out;

    dim3 block(256);                 // 4 waves = 4 rays per block
    dim3 grid(N_RAYS / 4);           // 65536 blocks
    volrend_kernel<<<grid, block, 0, stream>>>(sigma, colors, z_vals, rays_d, out);
}

// Round 6
// 140.429 us; speedup vs baseline: 1.0683x; 1.0683x over previous
//
#include <hip/hip_runtime.h>

#define N_RAYS 262144
#define N_SAMPLES 128

typedef float vf2 __attribute__((ext_vector_type(2)));

// One wave processes TWO rays (software-pipelined): all global loads for both
// rays are issued up front, so ray B's loads are in flight during ray A's
// scan/reduction chain. 2 consecutive samples per lane per ray.
struct RayIn {
    vf2 zv, sg, c01, c23, c45;
    float nrm;
};

__device__ __forceinline__ void process_ray(
    const int lane, const RayIn& in, const size_t rbase,
    float* __restrict__ out, float* sred6)
{
    const vf2 zv = in.zv, sg = in.sg;

    // ---- dists ----
    const float z_next = __shfl_down(zv.x, 1, 64);       // z[s0+2]
    const float dist0 = (zv.y - zv.x) * in.nrm;
    const float dist1 = ((lane & 63) == 63) ? (1e10f * in.nrm)
                                            : (z_next - zv.y) * in.nrm;

    // ---- alpha / survival ----
    const float e0 = __expf(-fmaxf(sg.x, 0.0f) * dist0);
    const float e1 = __expf(-fmaxf(sg.y, 0.0f) * dist1);
    const float alpha0 = 1.0f - e0;
    const float alpha1 = 1.0f - e1;
    const float a0 = e0 + 1e-10f;
    const float a1 = e1 + 1e-10f;

    // ---- exclusive prefix product (2/lane, 64 lanes) ----
    float scan = a0 * a1;
    #pragma unroll
    for (int off = 1; off < 64; off <<= 1) {
        const float n = __shfl_up(scan, off, 64);
        if (lane >= off) scan *= n;
    }
    float excl = __shfl_up(scan, 1, 64);
    if (lane == 0) excl = 1.0f;

    const float w0 = excl * alpha0;
    const float w1 = excl * a0 * alpha1;

    // ---- weights store (non-temporal, coalesced 512B/wave) ----
    const size_t R = N_RAYS;
    vf2 wv; wv.x = w0; wv.y = w1;
    __builtin_nontemporal_store(
        wv, reinterpret_cast<vf2*>(out + 3 * R + rbase + lane * 2));

    // ---- reductions ----
    float acc   = w0 + w1;
    float depth = w0 * zv.x     + w1 * zv.y;
    float cr    = w0 * in.c01.x + w1 * in.c23.y;
    float cg    = w0 * in.c01.y + w1 * in.c45.x;
    float cb    = w0 * in.c23.x + w1 * in.c45.y;
    #pragma unroll
    for (int off = 32; off; off >>= 1) {
        acc   += __shfl_xor(acc,   off, 64);
        depth += __shfl_xor(depth, off, 64);
        cr    += __shfl_xor(cr,    off, 64);
        cg    += __shfl_xor(cg,    off, 64);
        cb    += __shfl_xor(cb,    off, 64);
    }

    if (lane == 0) {
        sred6[0] = cr;
        sred6[1] = cg;
        sred6[2] = cb;
        sred6[3] = depth;
        sred6[4] = 1.0f / fmaxf(1e-10f, depth / acc);
        sred6[5] = acc;
    }
}

__device__ __forceinline__ RayIn load_ray(
    const int lane, const size_t rbase,
    const float* __restrict__ sigma, const float* __restrict__ colors,
    const float* __restrict__ z_vals, const float* __restrict__ rays_d,
    const int ray)
{
    RayIn r;
    const int s0 = lane * 2;
    r.zv = __builtin_nontemporal_load(
        reinterpret_cast<const vf2*>(z_vals + rbase + s0));
    r.sg = __builtin_nontemporal_load(
        reinterpret_cast<const vf2*>(sigma + rbase + s0));
    const float* cbase = colors + rbase * 3 + (size_t)s0 * 3;
    r.c01 = __builtin_nontemporal_load(reinterpret_cast<const vf2*>(cbase + 0));
    r.c23 = __builtin_nontemporal_load(reinterpret_cast<const vf2*>(cbase + 2));
    r.c45 = __builtin_nontemporal_load(reinterpret_cast<const vf2*>(cbase + 4));
    const float dx = rays_d[ray * 3 + 0];
    const float dy = rays_d[ray * 3 + 1];
    const float dz = rays_d[ray * 3 + 2];
    r.nrm = sqrtf(dx * dx + dy * dy + dz * dz);
    return r;
}

__global__ __launch_bounds__(256) void volrend_kernel(
    const float* __restrict__ sigma,
    const float* __restrict__ colors,
    const float* __restrict__ z_vals,
    const float* __restrict__ rays_d,
    float* __restrict__ out)
{
    const int wid  = threadIdx.x >> 6;   // wave in block: 0..3
    const int lane = threadIdx.x & 63;
    const int rayA = blockIdx.x * 8 + wid * 2;   // wave handles rays 2w, 2w+1
    const int rayB = rayA + 1;

    __shared__ float sred[8][6];         // per-ray: cr,cg,cb,depth,disp,acc

    const size_t rbaseA = (size_t)rayA * N_SAMPLES;
    const size_t rbaseB = (size_t)rayB * N_SAMPLES;

    // ---- issue ALL loads for BOTH rays up front (max MLP) ----
    const RayIn inA = load_ray(lane, rbaseA, sigma, colors, z_vals, rays_d, rayA);
    const RayIn inB = load_ray(lane, rbaseB, sigma, colors, z_vals, rays_d, rayB);

    // ---- compute ray A while ray B's loads are in flight ----
    process_ray(lane, inA, rbaseA, out, sred[wid * 2 + 0]);
    process_ray(lane, inB, rbaseB, out, sred[wid * 2 + 1]);

    __syncthreads();

    // ---- coalesced epilogue (8 rays per block) ----
    // out layout (flat, f32): rgb[R,3] | weights[R,128] | depth[R] | disp[R] | acc[R]
    const size_t R = N_RAYS;
    const int t = threadIdx.x;
    if (t < 24) {                       // rgb: 24 consecutive floats per block
        out[(size_t)blockIdx.x * 24 + t] = sred[t / 3][t % 3];
    } else if (t < 32) {                // depth: 8 consecutive floats
        out[131 * R + (size_t)blockIdx.x * 8 + (t - 24)] = sred[t - 24][3];
    } else if (t < 40) {                // disp
        out[132 * R + (size_t)blockIdx.x * 8 + (t - 32)] = sred[t - 32][4];
    } else if (t < 48) {                // acc
        out[133 * R + (size_t)blockIdx.x * 8 + (t - 40)] = sred[t - 40][5];
    }
}

extern "C" void kernel_launch(void* const* d_in, const int* in_sizes, int n_in,
                              void* d_out, int out_size, void* d_ws, size_t ws_size,
                              hipStream_t stream) {
    const float* sigma  = (const float*)d_in[0];
    const float* colors = (const float*)d_in[1];
    const float* z_vals = (const float*)d_in[2];
    const float* rays_d = (const float*)d_in[3];
    float* out = (float*)d_out;

    dim3 block(256);                 // 4 waves = 8 rays per block
    dim3 grid(N_RAYS / 8);           // 32768 blocks
    volrend_kernel<<<grid, block, 0, stream>>>(sigma, colors, z_vals, rays_d, out);
}